// Round 10
// baseline (336.402 us; speedup 1.0000x reference)
//
#include <hip/hip_runtime.h>

// ---------------------------------------------------------------------------
// Multi-gate MoE: x[16384,1024] -> experts (2x Linear+ReLU, E=8) -> 4 gates.
// GEMM1: 256x256 tile, 8 waves, BK=64, 4-phase/K-tile pipeline (round-3
//   cadence/ledger, unchanged) but with 32x32x16 MFMA (2x FLOP/inst, higher
//   pipe ceiling 2495 vs 2075 TF; B-frag reads halved).
// gates_k: fused x->bf16 convert (block converts its 64 rows, then MFMA).
// GEMM2: 128x128 gemm_bt, XCD-paired flat grid. combine: elementwise pass.
// ---------------------------------------------------------------------------

typedef __attribute__((ext_vector_type(8))) __bf16 bf16x8;
typedef __attribute__((ext_vector_type(4))) float f32x4;
typedef __attribute__((ext_vector_type(16))) float f32x16;
typedef __attribute__((ext_vector_type(8))) unsigned short u16x8;

__device__ __forceinline__ float bf2f(unsigned short u) {
  union { unsigned int i; float f; } x;
  x.i = ((unsigned int)u) << 16;
  return x.f;
}

__device__ __forceinline__ unsigned short f2bf(float f) {
  union { float f; unsigned int i; } x;
  x.f = f;
  unsigned int r = x.i + 0x7FFFu + ((x.i >> 16) & 1u);  // round-to-nearest-even
  return (unsigned short)(r >> 16);
}

__device__ __forceinline__ void gload_lds16(const unsigned short* g, unsigned short* l) {
  __builtin_amdgcn_global_load_lds(
      (const __attribute__((address_space(1))) void*)g,
      (__attribute__((address_space(3))) void*)l, 16, 0, 0);
}

// --------------------------- fp32 -> bf16 convert ---------------------------
__global__ void cvt_k(const float* __restrict__ in, unsigned short* __restrict__ out, int n4) {
  int i = blockIdx.x * blockDim.x + threadIdx.x;
  if (i >= n4) return;
  float4 v = ((const float4*)in)[i];
  ushort4 o;
  o.x = f2bf(v.x); o.y = f2bf(v.y); o.z = f2bf(v.z); o.w = f2bf(v.w);
  ((ushort4*)out)[i] = o;
}

// ---------------- gates: x-convert + logits + softmax (fused) ---------------
// Block = 64 rows. Prologue converts x[rows] -> xb[rows] (L2-hot), then the
// 4 waves compute the 32 gate logits per row via MFMA + 8-lane softmax.
__global__ __launch_bounds__(256) void gates_k(
    const float* __restrict__ x,             // [16384,1024] fp32
    unsigned short* __restrict__ xb,         // [16384,1024] bf16 (written here)
    const unsigned short* __restrict__ Wgb,  // [32,1024] bf16
    const float* __restrict__ bg,            // [32]
    float* __restrict__ gw)                  // [16384,32] fp32 softmaxed
{
  const int rowbase = blockIdx.x * 64;
  {
    const float4* xsrc = (const float4*)(x + (size_t)rowbase * 1024);
    ushort4* xdst = (ushort4*)(xb + (size_t)rowbase * 1024);
    for (int i = threadIdx.x; i < 64 * 256; i += 256) {
      float4 v = xsrc[i];
      ushort4 o;
      o.x = f2bf(v.x); o.y = f2bf(v.y); o.z = f2bf(v.z); o.w = f2bf(v.w);
      xdst[i] = o;
    }
  }
  __syncthreads();

  const int lane = threadIdx.x & 63;
  const int wid = threadIdx.x >> 6;
  const int brow = rowbase + wid * 16;
  const int l15 = lane & 15, lhi = lane >> 4;

  f32x4 acc0 = {0.f, 0.f, 0.f, 0.f};
  f32x4 acc1 = {0.f, 0.f, 0.f, 0.f};
  for (int k0 = 0; k0 < 1024; k0 += 32) {
    bf16x8 a  = *(const bf16x8*)&xb[(size_t)(brow + l15) * 1024 + k0 + lhi * 8];
    bf16x8 b0 = *(const bf16x8*)&Wgb[(size_t)l15 * 1024 + k0 + lhi * 8];
    bf16x8 b1 = *(const bf16x8*)&Wgb[(size_t)(16 + l15) * 1024 + k0 + lhi * 8];
    acc0 = __builtin_amdgcn_mfma_f32_16x16x32_bf16(a, b0, acc0, 0, 0, 0);
    acc1 = __builtin_amdgcn_mfma_f32_16x16x32_bf16(a, b1, acc1, 0, 0, 0);
  }
  const float bg0 = bg[l15];
  const float bg1 = bg[16 + l15];
#pragma unroll
  for (int r = 0; r < 4; ++r) {
    float v0 = acc0[r] + bg0;
    float v1 = acc1[r] + bg1;
    float m0 = v0, m1 = v1;
#pragma unroll
    for (int d = 1; d <= 4; d <<= 1) {
      m0 = fmaxf(m0, __shfl_xor(m0, d));
      m1 = fmaxf(m1, __shfl_xor(m1, d));
    }
    float e0 = __expf(v0 - m0), e1 = __expf(v1 - m1);
    float s0 = e0, s1 = e1;
#pragma unroll
    for (int d = 1; d <= 4; d <<= 1) {
      s0 += __shfl_xor(s0, d);
      s1 += __shfl_xor(s1, d);
    }
    int b = brow + lhi * 4 + r;
    gw[(size_t)b * 32 + l15]      = e0 / s0;
    gw[(size_t)b * 32 + 16 + l15] = e1 / s1;
  }
}

// --------------------------- 256x256 pipelined GEMM (B^T) -------------------
// Round-3 cadence/ledger. LDS: A slot s @ s*32768, B slot s @ 65536+s*32768;
// granule swizzle g_phys = g_log ^ (row&7). MFMA 32x32x16 (swapped operands):
//   A-op frag: row = lane&31, k = 8*(lane>>5)+j (8 consecutive bf16)
//   C/D: m = lane&31 (Y/col), n = (reg&3)+8*(reg>>2)+4*(lane>>5) (X/row)
template <bool RELU>
__global__ __launch_bounds__(512, 2) void gemm256(
    const unsigned short* __restrict__ A, int lda, int aZ,
    const unsigned short* __restrict__ B,     // [z][N][K]
    const float* __restrict__ bias,           // [z][N]
    unsigned short* __restrict__ C, int ldc, int cZ,
    int tilesN, int N, int K)
{
  extern __shared__ char smem_raw[];
  unsigned short* lds = (unsigned short*)smem_raw;
  char* ldsb = (char*)smem_raw;

  const int tid = threadIdx.x;
  const int lane = tid & 63, wid = tid >> 6;
  const int wr = wid >> 2, wc = wid & 3;
  const int l31 = lane & 31, hi = lane >> 5;

  const int nwg = gridDim.x;
  const int cpx = nwg >> 3;
  const int wg = blockIdx.x;
  const int swz = (wg & 7) * cpx + (wg >> 3);
  const int rt = swz / tilesN, ct = swz - rt * tilesN;
  const int brow = rt * 256, bcol = ct * 256;
  const int e = blockIdx.z;

  const unsigned short* Ab = A + (size_t)e * aZ + (size_t)brow * lda;
  const unsigned short* Bb = B + (size_t)e * N * K + (size_t)bcol * K;
  const float* biasb = bias + (size_t)e * N;
  unsigned short* Cb = C + (size_t)e * cZ;

  const int NT = K >> 6;
  const int NI = NT >> 1;

  // staging constants (unit = 64 rows x 64 cols, 1 load/thread)
  const int trow = tid >> 3;
  const int cg8 = (((tid & 7) ^ (trow & 7)) << 3);

  // ds_read constants: byte col = ((ks<<5)|(hi<<4)) ^ ((row&7)<<4), row&7==lane&7
  const int axor = (lane & 7) << 4;
  int koff[4];
#pragma unroll
  for (int ks = 0; ks < 4; ++ks) koff[ks] = ((ks << 5) | (hi << 4)) ^ axor;

  const char* pA = ldsb + wr * 16384 + l31 * 128;          // + slot*32768 + mi*4096
  const char* pB = ldsb + 65536 + wc * 8192 + l31 * 128;   // + slot*32768 + ni*4096

  // bias vectors: col = bcol + wc*64 + ni*32 + rq*8 + hi*4 (+0..3)
  f32x4 bias4[2][4];
#pragma unroll
  for (int ni = 0; ni < 2; ++ni)
#pragma unroll
    for (int rq = 0; rq < 4; ++rq)
      bias4[ni][rq] = *(const f32x4*)&biasb[bcol + wc * 64 + ni * 32 + rq * 8 + hi * 4];

  f32x16 acc[4][2];
#pragma unroll
  for (int m = 0; m < 4; ++m)
#pragma unroll
    for (int n = 0; n < 2; ++n)
#pragma unroll
      for (int r = 0; r < 16; ++r) acc[m][n][r] = 0.f;

  auto STAGE_A = [&](int slot, int t, int u) {
    gload_lds16(Ab + (size_t)(u * 64 + trow) * lda + (t * 64 + cg8),
                lds + slot * 16384 + u * 4096 + wid * 512);
  };
  auto STAGE_B = [&](int slot, int t, int u) {
    gload_lds16(Bb + (size_t)(u * 64 + trow) * K + (t * 64 + cg8),
                lds + 32768 + slot * 16384 + u * 4096 + wid * 512);
  };

  // prologue: stage K-tile 0 into slot 0, full drain once (also drains bias)
#pragma unroll
  for (int u = 0; u < 4; ++u) STAGE_B(0, 0, u);
#pragma unroll
  for (int u = 0; u < 4; ++u) STAGE_A(0, 0, u);
  asm volatile("s_waitcnt vmcnt(0)" ::: "memory");
  __builtin_amdgcn_s_barrier();

  // one K-tile = 4 phases; stages target slot^1 / K-tile tn (round-3 ledger).
  auto ktile = [&](int slot, int tn, bool stageNext) {
    bf16x8 af[2][4], bf[2][4];
    // ---- P1: read af mi0,mi1 (8) + bf n0 (4); stage B u0,u1; MFMA (mi01,n0)
#pragma unroll
    for (int mi = 0; mi < 2; ++mi)
#pragma unroll
      for (int ks = 0; ks < 4; ++ks)
        af[mi][ks] = *(const bf16x8*)(pA + slot * 32768 + mi * 4096 + koff[ks]);
#pragma unroll
    for (int ks = 0; ks < 4; ++ks)
      bf[0][ks] = *(const bf16x8*)(pB + slot * 32768 + koff[ks]);
    if (stageNext) { STAGE_B(slot ^ 1, tn, 0); STAGE_B(slot ^ 1, tn, 1); }
    __builtin_amdgcn_s_barrier();
    __builtin_amdgcn_s_setprio(1);
#pragma unroll
    for (int ks = 0; ks < 4; ++ks)
#pragma unroll
      for (int mi = 0; mi < 2; ++mi)
        acc[mi][0] = __builtin_amdgcn_mfma_f32_32x32x16_bf16(bf[0][ks], af[mi][ks], acc[mi][0], 0, 0, 0);
    __builtin_amdgcn_s_setprio(0);
    __builtin_amdgcn_s_barrier();

    // ---- P2: read bf n1 (4); stage B u2,u3; MFMA (mi01,n1); vmcnt(4)
#pragma unroll
    for (int ks = 0; ks < 4; ++ks)
      bf[1][ks] = *(const bf16x8*)(pB + slot * 32768 + 4096 + koff[ks]);
    if (stageNext) { STAGE_B(slot ^ 1, tn, 2); STAGE_B(slot ^ 1, tn, 3); }
    __builtin_amdgcn_s_barrier();
    __builtin_amdgcn_s_setprio(1);
#pragma unroll
    for (int ks = 0; ks < 4; ++ks)
#pragma unroll
      for (int mi = 0; mi < 2; ++mi)
        acc[mi][1] = __builtin_amdgcn_mfma_f32_32x32x16_bf16(bf[1][ks], af[mi][ks], acc[mi][1], 0, 0, 0);
    __builtin_amdgcn_s_setprio(0);
    asm volatile("s_waitcnt vmcnt(4)" ::: "memory");
    __builtin_amdgcn_s_barrier();

    // ---- P3: read af mi2,mi3 (8); stage A u0,u2; MFMA (mi23,n0)
#pragma unroll
    for (int mi = 0; mi < 2; ++mi)
#pragma unroll
      for (int ks = 0; ks < 4; ++ks)
        af[mi][ks] = *(const bf16x8*)(pA + slot * 32768 + (2 + mi) * 4096 + koff[ks]);
    if (stageNext) { STAGE_A(slot ^ 1, tn, 0); STAGE_A(slot ^ 1, tn, 2); }
    __builtin_amdgcn_s_barrier();
    __builtin_amdgcn_s_setprio(1);
#pragma unroll
    for (int ks = 0; ks < 4; ++ks)
#pragma unroll
      for (int mi = 0; mi < 2; ++mi)
        acc[2 + mi][0] = __builtin_amdgcn_mfma_f32_32x32x16_bf16(bf[0][ks], af[mi][ks], acc[2 + mi][0], 0, 0, 0);
    __builtin_amdgcn_s_setprio(0);
    __builtin_amdgcn_s_barrier();

    // ---- P4: stage A u1,u3; MFMA (mi23,n1); vmcnt(2)
    if (stageNext) { STAGE_A(slot ^ 1, tn, 1); STAGE_A(slot ^ 1, tn, 3); }
    __builtin_amdgcn_s_barrier();
    __builtin_amdgcn_s_setprio(1);
#pragma unroll
    for (int ks = 0; ks < 4; ++ks)
#pragma unroll
      for (int mi = 0; mi < 2; ++mi)
        acc[2 + mi][1] = __builtin_amdgcn_mfma_f32_32x32x16_bf16(bf[1][ks], af[mi][ks], acc[2 + mi][1], 0, 0, 0);
    __builtin_amdgcn_s_setprio(0);
    asm volatile("s_waitcnt vmcnt(2)" ::: "memory");
    __builtin_amdgcn_s_barrier();
  };

#pragma unroll 1
  for (int i = 0; i < NI; ++i) {
    ktile(0, 2 * i + 1, true);
    ktile(1, 2 * i + 2, (2 * i + 2) < NT);
  }

  // epilogue: m = brow+wr*128+mi*32+l31; n = ni*32 + rq*8 + hi*4 + (0..3)
#pragma unroll
  for (int mi = 0; mi < 4; ++mi) {
    const size_t rowoff = (size_t)(brow + wr * 128 + mi * 32 + l31) * ldc;
#pragma unroll
    for (int ni = 0; ni < 2; ++ni) {
#pragma unroll
      for (int rq = 0; rq < 4; ++rq) {
        const int col = bcol + wc * 64 + ni * 32 + rq * 8 + hi * 4;
        float v0 = acc[mi][ni][rq * 4 + 0] + bias4[ni][rq][0];
        float v1 = acc[mi][ni][rq * 4 + 1] + bias4[ni][rq][1];
        float v2 = acc[mi][ni][rq * 4 + 2] + bias4[ni][rq][2];
        float v3 = acc[mi][ni][rq * 4 + 3] + bias4[ni][rq][3];
        if (RELU) {
          v0 = v0 > 0.f ? v0 : 0.f;
          v1 = v1 > 0.f ? v1 : 0.f;
          v2 = v2 > 0.f ? v2 : 0.f;
          v3 = v3 > 0.f ? v3 : 0.f;
        }
        ushort4 o;
        o.x = f2bf(v0); o.y = f2bf(v1); o.z = f2bf(v2); o.w = f2bf(v3);
        *(ushort4*)&Cb[rowoff + col] = o;
      }
    }
  }
}

// --------------------------- 128x128 gemm_bt (GEMM2) ------------------------
// Flat grid x=256: m = (b>>4)*8 + (b&7), n = (b>>3)&1 (XCD L2 pairing).
template <bool RELU>
__global__ __launch_bounds__(256) void gemm_bt(
    const unsigned short* __restrict__ A, int lda, int aZ,
    const unsigned short* __restrict__ B,     // [z][N][K]
    const float* __restrict__ bias,           // [z][N]
    unsigned short* __restrict__ C, int ldc, int cZ,
    int N, int K)
{
  __shared__ unsigned short As[128 * 64];
  __shared__ unsigned short Bs[128 * 64];
  const int tid = threadIdx.x;
  const int wid = tid >> 6;
  const int lane = tid & 63;
  const int wr = wid >> 1, wc = wid & 1;
  const int l15 = lane & 15, lhi = lane >> 4;
  const int b = blockIdx.x;
  const int brow = (((b >> 4) << 3) + (b & 7)) * 128;
  const int bcol = ((b >> 3) & 1) * 128;
  const int e = blockIdx.z;

  const unsigned short* Ab = A + (size_t)e * aZ;
  const unsigned short* Bb = B + (size_t)e * N * K;
  const float* biasb = bias + (size_t)e * N;
  unsigned short* Cb = C + (size_t)e * cZ;

  const f32x4 zero = {0.f, 0.f, 0.f, 0.f};
  f32x4 acc[4][4];
#pragma unroll
  for (int m = 0; m < 4; ++m)
#pragma unroll
    for (int n = 0; n < 4; ++n) acc[m][n] = zero;

  const int srow = lane >> 3;
  const int scol = (lane & 7) * 8;
  const int rbase = wid * 32;

  for (int k0 = 0; k0 < K; k0 += 64) {
#pragma unroll
    for (int i = 0; i < 4; ++i) {
      int r = rbase + i * 8;
      gload_lds16(Ab + (size_t)(brow + r + srow) * lda + (k0 + scol), &As[r * 64]);
    }
#pragma unroll
    for (int i = 0; i < 4; ++i) {
      int r = rbase + i * 8;
      gload_lds16(Bb + (size_t)(bcol + r + srow) * K + (k0 + scol), &Bs[r * 64]);
    }
    __syncthreads();
#pragma unroll
    for (int kk = 0; kk < 2; ++kk) {
      bf16x8 af[4], bfr[4];
#pragma unroll
      for (int m = 0; m < 4; ++m)
        af[m] = *(const bf16x8*)&As[(wr * 64 + m * 16 + l15) * 64 + kk * 32 + lhi * 8];
#pragma unroll
      for (int n = 0; n < 4; ++n)
        bfr[n] = *(const bf16x8*)&Bs[(wc * 64 + n * 16 + l15) * 64 + kk * 32 + lhi * 8];
#pragma unroll
      for (int m = 0; m < 4; ++m)
#pragma unroll
        for (int n = 0; n < 4; ++n)
          acc[m][n] = __builtin_amdgcn_mfma_f32_16x16x32_bf16(af[m], bfr[n], acc[m][n], 0, 0, 0);
    }
    __syncthreads();
  }

#pragma unroll
  for (int n = 0; n < 4; ++n) {
    int col = bcol + wc * 64 + n * 16 + l15;
    float bv = biasb[col];
#pragma unroll
    for (int m = 0; m < 4; ++m) {
      int row0 = brow + wr * 64 + m * 16 + lhi * 4;
#pragma unroll
      for (int r = 0; r < 4; ++r) {
        float v = acc[m][n][r] + bv;
        if (RELU) v = v > 0.f ? v : 0.f;
        Cb[(size_t)(row0 + r) * ldc + col] = f2bf(v);
      }
    }
  }
}

// --------------------------- weighted combine -------------------------------
__global__ __launch_bounds__(256) void combine_k(
    const unsigned short* __restrict__ feats,  // [16384][8][256] bf16
    const float* __restrict__ gw,              // [16384][4][8]
    float* __restrict__ out)                   // [4][16384][256] fp32
{
  int tid = blockIdx.x * 256 + threadIdx.x;
  int b = tid >> 5;
  int d0 = (tid & 31) * 8;

  const f32x4* wv4 = (const f32x4*)(gw + (size_t)b * 32);
  f32x4 wv[8];
#pragma unroll
  for (int i = 0; i < 8; ++i) wv[i] = wv4[i];

  float o[4][8];
#pragma unroll
  for (int t = 0; t < 4; ++t)
#pragma unroll
    for (int j = 0; j < 8; ++j) o[t][j] = 0.f;

#pragma unroll
  for (int e = 0; e < 8; ++e) {
    u16x8 fv = *(const u16x8*)&feats[((size_t)b * 8 + e) * 256 + d0];
    float f[8];
#pragma unroll
    for (int j = 0; j < 8; ++j) f[j] = bf2f(fv[j]);
#pragma unroll
    for (int t = 0; t < 4; ++t) {
      float wt = wv[(t * 8 + e) >> 2][(t * 8 + e) & 3];
#pragma unroll
      for (int j = 0; j < 8; ++j) o[t][j] += wt * f[j];
    }
  }
#pragma unroll
  for (int t = 0; t < 4; ++t) {
    f32x4* dst = (f32x4*)(out + ((size_t)t * 16384 + b) * 256 + d0);
    f32x4 s0 = {o[t][0], o[t][1], o[t][2], o[t][3]};
    f32x4 s1 = {o[t][4], o[t][5], o[t][6], o[t][7]};
    dst[0] = s0;
    dst[1] = s1;
  }
}

// ---------------------------------------------------------------------------
extern "C" void kernel_launch(void* const* d_in, const int* in_sizes, int n_in,
                              void* d_out, int out_size, void* d_ws, size_t ws_size,
                              hipStream_t stream) {
  (void)in_sizes; (void)n_in; (void)out_size; (void)ws_size;
  const float* x  = (const float*)d_in[0];   // [16384,1024]
  const float* W1 = (const float*)d_in[1];   // [8,512,1024]
  const float* b1 = (const float*)d_in[2];   // [8,512]
  const float* W2 = (const float*)d_in[3];   // [8,256,512]
  const float* b2 = (const float*)d_in[4];   // [8,256]
  const float* Wg = (const float*)d_in[5];   // [4,8,1024]
  const float* bg = (const float*)d_in[6];   // [4,8]
  float* out = (float*)d_out;                // [4,16384,256]

  char* ws = (char*)d_ws;
  unsigned short* xb    = (unsigned short*)ws; ws += (size_t)16384 * 1024 * 2;  // 32 MB
  unsigned short* W1b   = (unsigned short*)ws; ws += (size_t)4096 * 1024 * 2;   // 8 MB
  unsigned short* W2b   = (unsigned short*)ws; ws += (size_t)2048 * 512 * 2;    // 2 MB
  unsigned short* Wgb   = (unsigned short*)ws; ws += (size_t)32 * 1024 * 2;     // 64 KB
  float*          gw    = (float*)ws;         ws += (size_t)16384 * 32 * 4;     // 2 MB
  unsigned short* H     = (unsigned short*)ws; ws += (size_t)16384 * 4096 * 2;  // 128 MB
  unsigned short* feats = (unsigned short*)ws; ws += (size_t)16384 * 2048 * 2;  // 64 MB

  // weight converts (x is converted inside gates_k)
  cvt_k<<<4096, 256, 0, stream>>>(W1, W1b, 4096 * 1024 / 4);
  cvt_k<<<1024, 256, 0, stream>>>(W2, W2b, 2048 * 512 / 4);
  cvt_k<<<32, 256, 0, stream>>>(Wg, Wgb, 32 * 1024 / 4);

  // gates: x->bf16 convert + logits + softmax
  gates_k<<<256, 256, 0, stream>>>(x, xb, Wgb, bg, gw);

  // layer1: H = relu(xb @ W1^T + b1), M=16384 N=4096 K=1024 -> 64x16=1024 wgs
  gemm256<true><<<dim3(1024, 1, 1), 512, 131072, stream>>>(
      xb, 1024, 0, W1b, b1, H, 4096, 0, /*tilesN*/16, 4096, 1024);

  // layer2 (batched over experts), XCD-paired flat grid (256 = 128m x 2n)
  gemm_bt<true><<<dim3(256, 1, 8), 256, 0, stream>>>(
      H, 4096, 512, W2b, b2, feats, 2048, 256, 256, 512);

  // combine: out[t,b,d] = sum_e feats[b,e,d] * gw[b,t,e]
  combine_k<<<2048, 256, 0, stream>>>(feats, gw, out);
}

// Round 11
// 295.881 us; speedup vs baseline: 1.1369x; 1.1369x over previous
//
#include <hip/hip_runtime.h>

// ---------------------------------------------------------------------------
// Multi-gate MoE: x[16384,1024] -> experts (2x Linear+ReLU, E=8) -> 4 gates.
// Best-measured composition (round 3 core + kept levers):
// GEMM1: 256x256 tile, 8 waves, BK=64, 4-phase/K-tile, 16x16x32 MFMA,
//   granule swizzle, counted vmcnt(4)/vmcnt(2), setprio, XCD swizzle.
// gates_k: fused x->bf16 convert + gate logits + softmax.
// GEMM2: 128x128 gemm_bt, XCD-paired flat grid. combine: elementwise pass.
// Rejected by measurement: deeper prefetch (r4), expert2 fusion (r5-7),
// nt-stores (r8: 2x write amplification), 32x32x16 MFMA (r10: bank conflicts).
// ---------------------------------------------------------------------------

typedef __attribute__((ext_vector_type(8))) __bf16 bf16x8;
typedef __attribute__((ext_vector_type(4))) float f32x4;
typedef __attribute__((ext_vector_type(8))) unsigned short u16x8;

__device__ __forceinline__ float bf2f(unsigned short u) {
  union { unsigned int i; float f; } x;
  x.i = ((unsigned int)u) << 16;
  return x.f;
}

__device__ __forceinline__ unsigned short f2bf(float f) {
  union { float f; unsigned int i; } x;
  x.f = f;
  unsigned int r = x.i + 0x7FFFu + ((x.i >> 16) & 1u);  // round-to-nearest-even
  return (unsigned short)(r >> 16);
}

__device__ __forceinline__ void gload_lds16(const unsigned short* g, unsigned short* l) {
  __builtin_amdgcn_global_load_lds(
      (const __attribute__((address_space(1))) void*)g,
      (__attribute__((address_space(3))) void*)l, 16, 0, 0);
}

// --------------------------- fp32 -> bf16 convert (weights) -----------------
__global__ void cvt_k(const float* __restrict__ in, unsigned short* __restrict__ out, int n4) {
  int i = blockIdx.x * blockDim.x + threadIdx.x;
  if (i >= n4) return;
  float4 v = ((const float4*)in)[i];
  ushort4 o;
  o.x = f2bf(v.x); o.y = f2bf(v.y); o.z = f2bf(v.z); o.w = f2bf(v.w);
  ((ushort4*)out)[i] = o;
}

// ---------------- gates: x-convert + logits + softmax (fused) ---------------
__global__ __launch_bounds__(256) void gates_k(
    const float* __restrict__ x,             // [16384,1024] fp32
    unsigned short* __restrict__ xb,         // [16384,1024] bf16 (written here)
    const unsigned short* __restrict__ Wgb,  // [32,1024] bf16
    const float* __restrict__ bg,            // [32]
    float* __restrict__ gw)                  // [16384,32] fp32 softmaxed
{
  const int rowbase = blockIdx.x * 64;
  {
    const float4* xsrc = (const float4*)(x + (size_t)rowbase * 1024);
    ushort4* xdst = (ushort4*)(xb + (size_t)rowbase * 1024);
    for (int i = threadIdx.x; i < 64 * 256; i += 256) {
      float4 v = xsrc[i];
      ushort4 o;
      o.x = f2bf(v.x); o.y = f2bf(v.y); o.z = f2bf(v.z); o.w = f2bf(v.w);
      xdst[i] = o;
    }
  }
  __syncthreads();

  const int lane = threadIdx.x & 63;
  const int wid = threadIdx.x >> 6;
  const int brow = rowbase + wid * 16;
  const int l15 = lane & 15, lhi = lane >> 4;

  f32x4 acc0 = {0.f, 0.f, 0.f, 0.f};
  f32x4 acc1 = {0.f, 0.f, 0.f, 0.f};
  for (int k0 = 0; k0 < 1024; k0 += 32) {
    bf16x8 a  = *(const bf16x8*)&xb[(size_t)(brow + l15) * 1024 + k0 + lhi * 8];
    bf16x8 b0 = *(const bf16x8*)&Wgb[(size_t)l15 * 1024 + k0 + lhi * 8];
    bf16x8 b1 = *(const bf16x8*)&Wgb[(size_t)(16 + l15) * 1024 + k0 + lhi * 8];
    acc0 = __builtin_amdgcn_mfma_f32_16x16x32_bf16(a, b0, acc0, 0, 0, 0);
    acc1 = __builtin_amdgcn_mfma_f32_16x16x32_bf16(a, b1, acc1, 0, 0, 0);
  }
  const float bg0 = bg[l15];
  const float bg1 = bg[16 + l15];
#pragma unroll
  for (int r = 0; r < 4; ++r) {
    float v0 = acc0[r] + bg0;
    float v1 = acc1[r] + bg1;
    float m0 = v0, m1 = v1;
#pragma unroll
    for (int d = 1; d <= 4; d <<= 1) {
      m0 = fmaxf(m0, __shfl_xor(m0, d));
      m1 = fmaxf(m1, __shfl_xor(m1, d));
    }
    float e0 = __expf(v0 - m0), e1 = __expf(v1 - m1);
    float s0 = e0, s1 = e1;
#pragma unroll
    for (int d = 1; d <= 4; d <<= 1) {
      s0 += __shfl_xor(s0, d);
      s1 += __shfl_xor(s1, d);
    }
    int b = brow + lhi * 4 + r;
    gw[(size_t)b * 32 + l15]      = e0 / s0;
    gw[(size_t)b * 32 + 16 + l15] = e1 / s1;
  }
}

// --------------------------- 256x256 pipelined GEMM (B^T) -------------------
// Round-3 cadence (best measured 159.8us). LDS: A slot s @ s*32768, B slot s
// @ 65536 + s*32768; granule swizzle g_phys = g_log ^ (row&7). 16x16x32 MFMA.
template <bool RELU>
__global__ __launch_bounds__(512, 2) void gemm256(
    const unsigned short* __restrict__ A, int lda, int aZ,
    const unsigned short* __restrict__ B,     // [z][N][K]
    const float* __restrict__ bias,           // [z][N]
    unsigned short* __restrict__ C, int ldc, int cZ,
    int tilesN, int N, int K)
{
  extern __shared__ char smem_raw[];
  unsigned short* lds = (unsigned short*)smem_raw;
  char* ldsb = (char*)smem_raw;

  const int tid = threadIdx.x;
  const int lane = tid & 63, wid = tid >> 6;
  const int wr = wid >> 2, wc = wid & 3;
  const int l15 = lane & 15, lhi = lane >> 4;

  const int nwg = gridDim.x;
  const int cpx = nwg >> 3;
  const int wg = blockIdx.x;
  const int swz = (wg & 7) * cpx + (wg >> 3);
  const int rt = swz / tilesN, ct = swz - rt * tilesN;
  const int brow = rt * 256, bcol = ct * 256;
  const int e = blockIdx.z;

  const unsigned short* Ab = A + (size_t)e * aZ + (size_t)brow * lda;
  const unsigned short* Bb = B + (size_t)e * N * K + (size_t)bcol * K;
  const float* biasb = bias + (size_t)e * N;
  unsigned short* Cb = C + (size_t)e * cZ;

  const int NT = K >> 6;
  const int NI = NT >> 1;

  const int trow = tid >> 3;
  const int cg8 = (((tid & 7) ^ (trow & 7)) << 3);

  const int axor = (l15 & 7) << 4;
  const int koff0 = (lhi << 4) ^ axor;
  const int koff1 = (64 + (lhi << 4)) ^ axor;

  const char* pA0 = ldsb + wr * 16384 + l15 * 128 + koff0;
  const char* pA1 = ldsb + wr * 16384 + l15 * 128 + koff1;
  const char* pB0 = ldsb + 65536 + wc * 8192 + l15 * 128 + koff0;
  const char* pB1 = ldsb + 65536 + wc * 8192 + l15 * 128 + koff1;

  f32x4 bias4[4];
#pragma unroll
  for (int nf = 0; nf < 4; ++nf)
    bias4[nf] = *(const f32x4*)&biasb[bcol + wc * 64 + nf * 16 + lhi * 4];

  const f32x4 zero = {0.f, 0.f, 0.f, 0.f};
  f32x4 acc[8][4];
#pragma unroll
  for (int m = 0; m < 8; ++m)
#pragma unroll
    for (int n = 0; n < 4; ++n) acc[m][n] = zero;

  auto STAGE_A = [&](int slot, int t, int u) {
    gload_lds16(Ab + (size_t)(u * 64 + trow) * lda + (t * 64 + cg8),
                lds + slot * 16384 + u * 4096 + wid * 512);
  };
  auto STAGE_B = [&](int slot, int t, int u) {
    gload_lds16(Bb + (size_t)(u * 64 + trow) * K + (t * 64 + cg8),
                lds + 32768 + slot * 16384 + u * 4096 + wid * 512);
  };

  // prologue: stage K-tile 0 into slot 0, full drain once
#pragma unroll
  for (int u = 0; u < 4; ++u) STAGE_B(0, 0, u);
#pragma unroll
  for (int u = 0; u < 4; ++u) STAGE_A(0, 0, u);
  asm volatile("s_waitcnt vmcnt(0)" ::: "memory");
  __builtin_amdgcn_s_barrier();

  auto ktile = [&](int slot, int tn, bool stageNext) {
    bf16x8 af[4][2], bfr[4][2];
    // ---- P1: read af m0-3 + bf n01; stage B u0,u1
#pragma unroll
    for (int mi = 0; mi < 4; ++mi) {
      af[mi][0] = *(const bf16x8*)(pA0 + slot * 32768 + mi * 2048);
      af[mi][1] = *(const bf16x8*)(pA1 + slot * 32768 + mi * 2048);
    }
#pragma unroll
    for (int n = 0; n < 2; ++n) {
      bfr[n][0] = *(const bf16x8*)(pB0 + slot * 32768 + n * 2048);
      bfr[n][1] = *(const bf16x8*)(pB1 + slot * 32768 + n * 2048);
    }
    if (stageNext) { STAGE_B(slot ^ 1, tn, 0); STAGE_B(slot ^ 1, tn, 1); }
    __builtin_amdgcn_s_barrier();
    __builtin_amdgcn_s_setprio(1);
#pragma unroll
    for (int kk = 0; kk < 2; ++kk)
#pragma unroll
      for (int mi = 0; mi < 4; ++mi)
#pragma unroll
        for (int n = 0; n < 2; ++n)
          acc[mi][n] = __builtin_amdgcn_mfma_f32_16x16x32_bf16(bfr[n][kk], af[mi][kk], acc[mi][n], 0, 0, 0);
    __builtin_amdgcn_s_setprio(0);
    __builtin_amdgcn_s_barrier();

    // ---- P2: read bf n23; stage B u2,u3; vmcnt(4)
#pragma unroll
    for (int n = 0; n < 2; ++n) {
      bfr[2 + n][0] = *(const bf16x8*)(pB0 + slot * 32768 + (2 + n) * 2048);
      bfr[2 + n][1] = *(const bf16x8*)(pB1 + slot * 32768 + (2 + n) * 2048);
    }
    if (stageNext) { STAGE_B(slot ^ 1, tn, 2); STAGE_B(slot ^ 1, tn, 3); }
    __builtin_amdgcn_s_barrier();
    __builtin_amdgcn_s_setprio(1);
#pragma unroll
    for (int kk = 0; kk < 2; ++kk)
#pragma unroll
      for (int mi = 0; mi < 4; ++mi)
#pragma unroll
        for (int n = 0; n < 2; ++n)
          acc[mi][2 + n] = __builtin_amdgcn_mfma_f32_16x16x32_bf16(bfr[2 + n][kk], af[mi][kk], acc[mi][2 + n], 0, 0, 0);
    __builtin_amdgcn_s_setprio(0);
    asm volatile("s_waitcnt vmcnt(4)" ::: "memory");
    __builtin_amdgcn_s_barrier();

    // ---- P3: read af m4-7; stage A u0,u2
#pragma unroll
    for (int mi = 0; mi < 4; ++mi) {
      af[mi][0] = *(const bf16x8*)(pA0 + slot * 32768 + 8192 + mi * 2048);
      af[mi][1] = *(const bf16x8*)(pA1 + slot * 32768 + 8192 + mi * 2048);
    }
    if (stageNext) { STAGE_A(slot ^ 1, tn, 0); STAGE_A(slot ^ 1, tn, 2); }
    __builtin_amdgcn_s_barrier();
    __builtin_amdgcn_s_setprio(1);
#pragma unroll
    for (int kk = 0; kk < 2; ++kk)
#pragma unroll
      for (int mi = 0; mi < 4; ++mi)
#pragma unroll
        for (int n = 0; n < 2; ++n)
          acc[4 + mi][n] = __builtin_amdgcn_mfma_f32_16x16x32_bf16(bfr[n][kk], af[mi][kk], acc[4 + mi][n], 0, 0, 0);
    __builtin_amdgcn_s_setprio(0);
    __builtin_amdgcn_s_barrier();

    // ---- P4: stage A u1,u3; vmcnt(2)
    if (stageNext) { STAGE_A(slot ^ 1, tn, 1); STAGE_A(slot ^ 1, tn, 3); }
    __builtin_amdgcn_s_barrier();
    __builtin_amdgcn_s_setprio(1);
#pragma unroll
    for (int kk = 0; kk < 2; ++kk)
#pragma unroll
      for (int mi = 0; mi < 4; ++mi)
#pragma unroll
        for (int n = 0; n < 2; ++n)
          acc[4 + mi][2 + n] = __builtin_amdgcn_mfma_f32_16x16x32_bf16(bfr[2 + n][kk], af[mi][kk], acc[4 + mi][2 + n], 0, 0, 0);
    __builtin_amdgcn_s_setprio(0);
    asm volatile("s_waitcnt vmcnt(2)" ::: "memory");
    __builtin_amdgcn_s_barrier();
  };

#pragma unroll 1
  for (int i = 0; i < NI; ++i) {
    ktile(0, 2 * i + 1, true);
    ktile(1, 2 * i + 2, (2 * i + 2) < NT);
  }

#pragma unroll
  for (int mf = 0; mf < 8; ++mf) {
    const size_t rowoff = (size_t)(brow + wr * 128 + mf * 16 + l15) * ldc;
#pragma unroll
    for (int nf = 0; nf < 4; ++nf) {
      const int col = bcol + wc * 64 + nf * 16 + lhi * 4;
      f32x4 v = acc[mf][nf];
      ushort4 o;
      float v0 = v[0] + bias4[nf][0];
      float v1 = v[1] + bias4[nf][1];
      float v2 = v[2] + bias4[nf][2];
      float v3 = v[3] + bias4[nf][3];
      if (RELU) {
        v0 = v0 > 0.f ? v0 : 0.f;
        v1 = v1 > 0.f ? v1 : 0.f;
        v2 = v2 > 0.f ? v2 : 0.f;
        v3 = v3 > 0.f ? v3 : 0.f;
      }
      o.x = f2bf(v0); o.y = f2bf(v1); o.z = f2bf(v2); o.w = f2bf(v3);
      *(ushort4*)&Cb[rowoff + col] = o;
    }
  }
}

// --------------------------- 128x128 gemm_bt (GEMM2) ------------------------
// Flat grid x=256: m = (b>>4)*8 + (b&7), n = (b>>3)&1 (XCD L2 pairing).
template <bool RELU>
__global__ __launch_bounds__(256) void gemm_bt(
    const unsigned short* __restrict__ A, int lda, int aZ,
    const unsigned short* __restrict__ B,     // [z][N][K]
    const float* __restrict__ bias,           // [z][N]
    unsigned short* __restrict__ C, int ldc, int cZ,
    int N, int K)
{
  __shared__ unsigned short As[128 * 64];
  __shared__ unsigned short Bs[128 * 64];
  const int tid = threadIdx.x;
  const int wid = tid >> 6;
  const int lane = tid & 63;
  const int wr = wid >> 1, wc = wid & 1;
  const int l15 = lane & 15, lhi = lane >> 4;
  const int b = blockIdx.x;
  const int brow = (((b >> 4) << 3) + (b & 7)) * 128;
  const int bcol = ((b >> 3) & 1) * 128;
  const int e = blockIdx.z;

  const unsigned short* Ab = A + (size_t)e * aZ;
  const unsigned short* Bb = B + (size_t)e * N * K;
  const float* biasb = bias + (size_t)e * N;
  unsigned short* Cb = C + (size_t)e * cZ;

  const f32x4 zero = {0.f, 0.f, 0.f, 0.f};
  f32x4 acc[4][4];
#pragma unroll
  for (int m = 0; m < 4; ++m)
#pragma unroll
    for (int n = 0; n < 4; ++n) acc[m][n] = zero;

  const int srow = lane >> 3;
  const int scol = (lane & 7) * 8;
  const int rbase = wid * 32;

  for (int k0 = 0; k0 < K; k0 += 64) {
#pragma unroll
    for (int i = 0; i < 4; ++i) {
      int r = rbase + i * 8;
      gload_lds16(Ab + (size_t)(brow + r + srow) * lda + (k0 + scol), &As[r * 64]);
    }
#pragma unroll
    for (int i = 0; i < 4; ++i) {
      int r = rbase + i * 8;
      gload_lds16(Bb + (size_t)(bcol + r + srow) * K + (k0 + scol), &Bs[r * 64]);
    }
    __syncthreads();
#pragma unroll
    for (int kk = 0; kk < 2; ++kk) {
      bf16x8 af[4], bfr[4];
#pragma unroll
      for (int m = 0; m < 4; ++m)
        af[m] = *(const bf16x8*)&As[(wr * 64 + m * 16 + l15) * 64 + kk * 32 + lhi * 8];
#pragma unroll
      for (int n = 0; n < 4; ++n)
        bfr[n] = *(const bf16x8*)&Bs[(wc * 64 + n * 16 + l15) * 64 + kk * 32 + lhi * 8];
#pragma unroll
      for (int m = 0; m < 4; ++m)
#pragma unroll
        for (int n = 0; n < 4; ++n)
          acc[m][n] = __builtin_amdgcn_mfma_f32_16x16x32_bf16(af[m], bfr[n], acc[m][n], 0, 0, 0);
    }
    __syncthreads();
  }

#pragma unroll
  for (int n = 0; n < 4; ++n) {
    int col = bcol + wc * 64 + n * 16 + l15;
    float bv = biasb[col];
#pragma unroll
    for (int m = 0; m < 4; ++m) {
      int row0 = brow + wr * 64 + m * 16 + lhi * 4;
#pragma unroll
      for (int r = 0; r < 4; ++r) {
        float v = acc[m][n][r] + bv;
        if (RELU) v = v > 0.f ? v : 0.f;
        Cb[(size_t)(row0 + r) * ldc + col] = f2bf(v);
      }
    }
  }
}

// --------------------------- weighted combine -------------------------------
__global__ __launch_bounds__(256) void combine_k(
    const unsigned short* __restrict__ feats,  // [16384][8][256] bf16
    const float* __restrict__ gw,              // [16384][4][8]
    float* __restrict__ out)                   // [4][16384][256] fp32
{
  int tid = blockIdx.x * 256 + threadIdx.x;
  int b = tid >> 5;
  int d0 = (tid & 31) * 8;

  const f32x4* wv4 = (const f32x4*)(gw + (size_t)b * 32);
  f32x4 wv[8];
#pragma unroll
  for (int i = 0; i < 8; ++i) wv[i] = wv4[i];

  float o[4][8];
#pragma unroll
  for (int t = 0; t < 4; ++t)
#pragma unroll
    for (int j = 0; j < 8; ++j) o[t][j] = 0.f;

#pragma unroll
  for (int e = 0; e < 8; ++e) {
    u16x8 fv = *(const u16x8*)&feats[((size_t)b * 8 + e) * 256 + d0];
    float f[8];
#pragma unroll
    for (int j = 0; j < 8; ++j) f[j] = bf2f(fv[j]);
#pragma unroll
    for (int t = 0; t < 4; ++t) {
      float wt = wv[(t * 8 + e) >> 2][(t * 8 + e) & 3];
#pragma unroll
      for (int j = 0; j < 8; ++j) o[t][j] += wt * f[j];
    }
  }
#pragma unroll
  for (int t = 0; t < 4; ++t) {
    f32x4* dst = (f32x4*)(out + ((size_t)t * 16384 + b) * 256 + d0);
    f32x4 s0 = {o[t][0], o[t][1], o[t][2], o[t][3]};
    f32x4 s1 = {o[t][4], o[t][5], o[t][6], o[t][7]};
    dst[0] = s0;
    dst[1] = s1;
  }
}

// ---------------------------------------------------------------------------
extern "C" void kernel_launch(void* const* d_in, const int* in_sizes, int n_in,
                              void* d_out, int out_size, void* d_ws, size_t ws_size,
                              hipStream_t stream) {
  (void)in_sizes; (void)n_in; (void)out_size; (void)ws_size;
  const float* x  = (const float*)d_in[0];   // [16384,1024]
  const float* W1 = (const float*)d_in[1];   // [8,512,1024]
  const float* b1 = (const float*)d_in[2];   // [8,512]
  const float* W2 = (const float*)d_in[3];   // [8,256,512]
  const float* b2 = (const float*)d_in[4];   // [8,256]
  const float* Wg = (const float*)d_in[5];   // [4,8,1024]
  const float* bg = (const float*)d_in[6];   // [4,8]
  float* out = (float*)d_out;                // [4,16384,256]

  char* ws = (char*)d_ws;
  unsigned short* xb    = (unsigned short*)ws; ws += (size_t)16384 * 1024 * 2;  // 32 MB
  unsigned short* W1b   = (unsigned short*)ws; ws += (size_t)4096 * 1024 * 2;   // 8 MB
  unsigned short* W2b   = (unsigned short*)ws; ws += (size_t)2048 * 512 * 2;    // 2 MB
  unsigned short* Wgb   = (unsigned short*)ws; ws += (size_t)32 * 1024 * 2;     // 64 KB
  float*          gw    = (float*)ws;         ws += (size_t)16384 * 32 * 4;     // 2 MB
  unsigned short* H     = (unsigned short*)ws; ws += (size_t)16384 * 4096 * 2;  // 128 MB
  unsigned short* feats = (unsigned short*)ws; ws += (size_t)16384 * 2048 * 2;  // 64 MB

  // weight converts (x is converted inside gates_k)
  cvt_k<<<4096, 256, 0, stream>>>(W1, W1b, 4096 * 1024 / 4);
  cvt_k<<<1024, 256, 0, stream>>>(W2, W2b, 2048 * 512 / 4);
  cvt_k<<<32, 256, 0, stream>>>(Wg, Wgb, 32 * 1024 / 4);

  // gates: x->bf16 convert + logits + softmax
  gates_k<<<256, 256, 0, stream>>>(x, xb, Wgb, bg, gw);

  // layer1: H = relu(xb @ W1^T + b1), M=16384 N=4096 K=1024 -> 64x16=1024 wgs
  gemm256<true><<<dim3(1024, 1, 1), 512, 131072, stream>>>(
      xb, 1024, 0, W1b, b1, H, 4096, 0, /*tilesN*/16, 4096, 1024);

  // layer2 (batched over experts), XCD-paired flat grid (256 = 128m x 2n)
  gemm_bt<true><<<dim3(256, 1, 8), 256, 0, stream>>>(
      H, 4096, 512, W2b, b2, feats, 2048, 256, 256, 512);

  // combine: out[t,b,d] = sum_e feats[b,e,d] * gw[b,t,e]
  combine_k<<<2048, 256, 0, stream>>>(feats, gw, out);
}